// Round 9
// baseline (151.225 us; speedup 1.0000x reference)
//
#include <hip/hip_runtime.h>
#include <stdint.h>

#define OH 250
#define OW 250
#define NPTS (OH*OW)        // 62500
#define NSEG 4              // y batches only (x-side is mathematically dead; verified R2-R8)
#define D 147               // 3*7*7
#define CH 3
#define IMH 256
#define IMW 256
#define NITER 17            // ceil(log2(62500)) + 1, per reference
#define NBUCK 8192
#define CAP 128             // slots/bucket; central lambda ~24, P(>128) ~ e-50
#define SIG0 12.124355652982141  // sqrt(147): projection stddev model (bucketing only)
#define LT 12               // probe-tree levels cached in LDS (nodes 1..4095)

typedef unsigned long long u64;
typedef unsigned int u32;

// workspace layout (bytes)
#define OFF_SREC  0UL          // u64[4*8192*128] = 33,554,432
#define OFF_A     33554432UL   // u32[4*62500]    = 1,000,000
#define OFF_WTS   34554432UL   // f64[4*147]      = 4,704
#define OFF_CURS  34559136UL   // u32[4*8192]     = 131,072
#define OFF_BASES 34690208UL   // u32[4*8193]     = 131,088
#define OFF_SUMS  34821296UL   // u64[4]          = 32
#define OFF_TICK  34821328UL   // u32[2]          = 8
#define OFF_OFLOW 34821336UL   // u32[1]          = 4
#define WS_NEED   34821340UL

__device__ __forceinline__ u64 packd(double f) {
  u64 u = (u64)__double_as_longlong(f);
  return (u & 0x8000000000000000ULL) ? ~u : (u | 0x8000000000000000ULL);
}

// bucket from the 47-bit-truncated transformed key (monotone with key order)
__device__ __forceinline__ int bucket_of(u64 rec) {
  u64 t = rec & ~0x1FFFFULL;
  u64 bits = (t & 0x8000000000000000ULL) ? (t & 0x7FFFFFFFFFFFFFFFULL) : ~t;
  double v = __longlong_as_double((long long)bits);
  double z = (v + 4.0 * SIG0) * ((double)NBUCK / (8.0 * SIG0));
  int b = (z <= 0.0) ? 0 : (int)z;
  if (b > NBUCK - 1) b = NBUCK - 1;
  return b;
}

// ---- setup: blocks 0..3 weights (rand/std ddof=1, f64 -> global); rest zero ctrl ----
__global__ __launch_bounds__(256) void setup_kern(const float* __restrict__ rnd,
                                                  double* __restrict__ wts,
                                                  u32* __restrict__ curs,
                                                  u64* __restrict__ sums,
                                                  u32* __restrict__ tick,
                                                  u32* __restrict__ oflow) {
  int t = threadIdx.x;
  if (blockIdx.x < 4) {
    int b = blockIdx.x;
    int lane = t & 63;
    double v0 = (double)rnd[b * D + lane];
    double v1 = (double)rnd[b * D + lane + 64];
    double v2 = (lane + 128 < D) ? (double)rnd[b * D + lane + 128] : 0.0;
    double sm = v0 + v1 + v2;
    #pragma unroll
    for (int o = 32; o > 0; o >>= 1) sm += __shfl_xor(sm, o, 64);
    double mean = sm / (double)D;
    double d0 = v0 - mean, d1 = v1 - mean;
    double d2 = (lane + 128 < D) ? (v2 - mean) : 0.0;
    double ss = d0 * d0 + d1 * d1 + d2 * d2;
    #pragma unroll
    for (int o = 32; o > 0; o >>= 1) ss += __shfl_xor(ss, o, 64);
    double stdv = sqrt(ss / (double)(D - 1));
    if (t < 64) {                                  // one wave writes
      wts[b * D + lane] = v0 / stdv;
      wts[b * D + lane + 64] = v1 / stdv;
      if (lane + 128 < D) wts[b * D + lane + 128] = v2 / stdv;
    }
    if (b == 0 && t < 8) ((u32*)sums)[t] = 0u;
    if (b == 0 && t >= 8 && t < 10) tick[t - 8] = 0u;
    if (b == 0 && t == 10) oflow[0] = 0u;
  } else {
    int g = (blockIdx.x - 4) * 1024 + t * 4;       // 32 blocks cover 32768 u32
    if (g < NSEG * NBUCK) {
      curs[g] = 0u; curs[g + 1] = 0u; curs[g + 2] = 0u; curs[g + 3] = 0u;
    }
  }
}

// ---- conv (3x7x7, f64, exact R8 order) + direct bucket scatter + last-block scan tail ----
__global__ __launch_bounds__(256) void conv_kern(const float* __restrict__ y,
                                                 const double* __restrict__ wts,
                                                 u64* __restrict__ srec,
                                                 u32* __restrict__ curs,
                                                 u32* __restrict__ bases,
                                                 u32* __restrict__ tick,
                                                 u32* __restrict__ oflow) {
  __shared__ float tile[CH][22][22];
  __shared__ double w[D];
  __shared__ u32 spart[256];
  __shared__ u32 rank_s;
  int b = blockIdx.z;
  const float* in = y + (size_t)b * CH * IMH * IMW;
  int bi = blockIdx.y * 16, bj = blockIdx.x * 16;
  int tid = threadIdx.y * 16 + threadIdx.x;
  if (tid < D) w[tid] = wts[b * D + tid];
  for (int c = 0; c < CH; ++c)
    for (int t = tid; t < 22 * 22; t += 256) {
      int rr = t / 22, cc = t - rr * 22;
      int r = bi + rr, col = bj + cc;
      float v = 0.f;
      if (r < IMH && col < IMW) v = in[((size_t)c * IMH + r) * IMW + col];
      tile[c][rr][cc] = v;
    }
  __syncthreads();
  int i = bi + threadIdx.y, j = bj + threadIdx.x;
  if (i < OH && j < OW) {
    double acc = 0.0;
    #pragma unroll
    for (int c = 0; c < CH; ++c)
      #pragma unroll
      for (int ph = 0; ph < 7; ++ph)
        #pragma unroll
        for (int pw = 0; pw < 7; ++pw)
          acc = fma((double)tile[c][threadIdx.y + ph][threadIdx.x + pw],
                    w[c * 49 + ph * 7 + pw], acc);
    int n = i * OW + j;
    u64 rec = (packd(acc) & ~0x1FFFFULL) | (u64)(u32)n;
    int bk = b * NBUCK + bucket_of(rec);
    u32 pos = atomicAdd(&curs[bk], 1u);            // result used -> RMW complete pre-barrier
    if (pos < CAP) srec[(size_t)bk * CAP + pos] = rec;
    else atomicOr(oflow, 1u);                      // exactness tripwire
  }
  // ---- fence-free ticket: barrier drains this block's atomics, then count blocks ----
  __syncthreads();
  if (tid == 0) rank_s = atomicAdd(&tick[0], 1u);
  __syncthreads();
  if (rank_s != 16 * 16 * NSEG - 1) return;
  // winner: all blocks' curs RMWs complete at coherent point; scan counts -> bases
  for (int s = 0; s < NSEG; ++s) {
    u32 c[32]; u32 run = 0;
    #pragma unroll
    for (int m = 0; m < 32; ++m) {
      u32 v = __hip_atomic_load(&curs[s * NBUCK + tid * 32 + m],
                                __ATOMIC_RELAXED, __HIP_MEMORY_SCOPE_AGENT);
      c[m] = v > CAP ? CAP : v;
      run += c[m];
    }
    spart[tid] = run;
    __syncthreads();
    for (int off = 1; off < 256; off <<= 1) {
      u32 v = (tid >= off) ? spart[tid - off] : 0u;
      __syncthreads();
      spart[tid] += v;
      __syncthreads();
    }
    u32 ex = spart[tid] - run;
    #pragma unroll
    for (int m = 0; m < 32; ++m) {
      bases[s * (NBUCK + 1) + tid * 32 + m] = ex;
      ex += c[m];
    }
    if (tid == 255) {
      bases[s * (NBUCK + 1) + NBUCK] = ex;
      if (ex != NPTS) atomicOr(oflow, 2u);         // coherence/overflow tripwire (loud)
    }
    __syncthreads();
  }
}

// ---- one wave per bucket: exact rank sort (records all distinct), write argsort idx ----
__global__ __launch_bounds__(512) void bsort_kern(const u64* __restrict__ srec,
                                                  const u32* __restrict__ bases,
                                                  u32* __restrict__ a) {
  __shared__ u64 buf[8][CAP];
  int wid = threadIdx.x >> 6, lane = threadIdx.x & 63;
  int B = blockIdx.x * 8 + wid;                    // 32768 buckets total
  int seg = B / NBUCK, bk = B & (NBUCK - 1);
  u32 b0 = bases[seg * (NBUCK + 1) + bk];
  u32 b1 = bases[seg * (NBUCK + 1) + bk + 1];
  int n = (int)(b1 - b0);                          // <= CAP by scan clamp
  const u64* src = srec + (size_t)B * CAP;
  u32* dst = a + (size_t)seg * NPTS + b0;
  for (int i = lane; i < n; i += 64) buf[wid][i] = src[i];
  __syncthreads();
  for (int i = lane; i < n; i += 64) {
    u64 x = buf[wid][i];
    int r = 0;
    for (int j = 0; j < n; ++j) r += (buf[wid][j] < x);   // LDS broadcast, conflict-free
    dst[r] = (u32)(x & 0x1FFFFULL);
  }
}

// ---- loss: exact bisect replica with fixed probe tree (12 levels in LDS) + fused final ----
// grid (62, NSEG) x 256; each thread 4 interleaved searches in its segment.
#define TPS (62 * 256)                             // 15872 threads per segment
__global__ __launch_bounds__(256) void loss_kern(const u32* __restrict__ a_all,
                                                 u64* __restrict__ sums,
                                                 u32* __restrict__ tick,
                                                 const u32* __restrict__ oflow,
                                                 float* __restrict__ out,
                                                 int nblocks) {
  __shared__ u32 tval[1 << LT];                    // 4096 u32 = 16 KB
  __shared__ u64 parts[4];
  __shared__ u32 rank_s;
  int tid = threadIdx.x;
  int seg = blockIdx.y;
  const u32* A = a_all + (size_t)seg * NPTS;
  // build probe-value tree: node h (1-based heap), probe pos fixed by path replay
  for (int h = 1 + tid; h < (1 << LT); h += 256) {
    int d = 31 - __clz(h);
    int lo = 0, hi = NPTS;
    for (int k = d - 1; k >= 0; --k) {
      int mid = (lo + hi) >> 1;
      if (lo < hi) { if ((h >> k) & 1) lo = mid + 1; else hi = mid; }
    }
    int pos = (lo + hi) >> 1;
    if (pos > NPTS - 1) pos = NPTS - 1;
    tval[h] = A[pos];
  }
  __syncthreads();

  int base = blockIdx.x * 256 + tid;
  int vq[4], loq[4], hiq[4], hq[4];
  bool act[4];
  #pragma unroll
  for (int q = 0; q < 4; ++q) {
    int v = base + q * TPS;
    act[q] = v < NPTS;
    vq[q] = act[q] ? v : 0;
    loq[q] = 0; hiq[q] = NPTS; hq[q] = 1;
  }
  #pragma unroll
  for (int it = 0; it < LT; ++it) {                // LDS phase: probe value = tval[h]
    #pragma unroll
    for (int q = 0; q < 4; ++q) {
      int am = (int)tval[hq[q]];
      bool pred = am < vq[q];
      if (loq[q] < hiq[q]) {
        int mid = (loq[q] + hiq[q]) >> 1;
        if (pred) loq[q] = mid + 1; else hiq[q] = mid;
      }
      hq[q] = 2 * hq[q] + (pred ? 1 : 0);
    }
  }
  #pragma unroll
  for (int it = LT; it < NITER; ++it) {            // global phase
    #pragma unroll
    for (int q = 0; q < 4; ++q) {
      int mid = (loq[q] + hiq[q]) >> 1;
      int cm = mid > NPTS - 1 ? NPTS - 1 : mid;
      int am = (int)A[cm];
      if (loq[q] < hiq[q]) {
        if (am < vq[q]) loq[q] = mid + 1; else hiq[q] = mid;
      }
    }
  }
  u64 tsum = 0;
  #pragma unroll
  for (int q = 0; q < 4; ++q) {
    int lo = loq[q], v = vq[q];
    int pi = lo - 1; if (pi < 0) pi = 0; if (pi > NPTS - 1) pi = NPTS - 1;
    int ci = lo;     if (ci > NPTS - 1) ci = NPTS - 1;
    int ap = (int)A[pi], aa = (int)A[ci];
    int d1 = v - ap; if (d1 < 0) d1 = -d1;
    int d2 = v - aa; if (d2 < 0) d2 = -d2;
    bool tp = (lo > 0) && ((lo == NPTS) || (d1 < d2));
    long long dd = (long long)(v - (tp ? ap : aa));
    if (act[q]) tsum += (u64)(dd * dd);
  }
  for (int off = 32; off > 0; off >>= 1) tsum += __shfl_down(tsum, off, 64);
  int lane = tid & 63, wid = tid >> 6;
  if (lane == 0) parts[wid] = tsum;
  __syncthreads();
  if (tid == 0) {
    u64 bsum = parts[0] + parts[1] + parts[2] + parts[3];
    u64 old = atomicAdd(&sums[seg], bsum);
    asm volatile("" : : "v"(old) : "memory");      // force RMW completion before ticket
    rank_s = atomicAdd(&tick[1], 1u);
    if (rank_s == (u32)(nblocks - 1)) {            // fence-free fused final
      u32 of = __hip_atomic_load(oflow, __ATOMIC_RELAXED, __HIP_MEMORY_SCOPE_AGENT);
      if (of) { out[0] = 8.0e12f + 1.0e11f * (float)of; return; }
      double l = 0.0;
      for (int s = 0; s < NSEG; ++s) {
        u64 sv = __hip_atomic_load(&sums[s], __ATOMIC_RELAXED, __HIP_MEMORY_SCOPE_AGENT);
        l += (double)(long long)sv / (double)NPTS;
      }
      out[0] = (float)(l / 4.0);
    }
  }
}

__global__ void guard_kern(float* __restrict__ out) {
  if (threadIdx.x == 0 && blockIdx.x == 0) out[0] = 9.0e12f;
}

extern "C" void kernel_launch(void* const* d_in, const int* in_sizes, int n_in,
                              void* d_out, int out_size, void* d_ws, size_t ws_size,
                              hipStream_t stream) {
  (void)in_sizes; (void)n_in; (void)out_size;
  if (ws_size < WS_NEED) { guard_kern<<<1, 64, 0, stream>>>((float*)d_out); return; }
  const float* y   = (const float*)d_in[1];
  const float* rnd = (const float*)d_in[2];

  char* ws = (char*)d_ws;
  u64* srec   = (u64*)(ws + OFF_SREC);
  u32* aidx   = (u32*)(ws + OFF_A);
  double* wts = (double*)(ws + OFF_WTS);
  u32* curs   = (u32*)(ws + OFF_CURS);
  u32* bases  = (u32*)(ws + OFF_BASES);
  u64* sums   = (u64*)(ws + OFF_SUMS);
  u32* tick   = (u32*)(ws + OFF_TICK);
  u32* oflow  = (u32*)(ws + OFF_OFLOW);
  float* out  = (float*)d_out;

  setup_kern<<<36, 256, 0, stream>>>(rnd, wts, curs, sums, tick, oflow);
  conv_kern<<<dim3(16, 16, NSEG), dim3(16, 16), 0, stream>>>(y, wts, srec, curs, bases, tick, oflow);
  bsort_kern<<<NSEG * NBUCK / 8, 512, 0, stream>>>(srec, bases, aidx);
  loss_kern<<<dim3(62, NSEG), 256, 0, stream>>>(aidx, sums, tick, oflow, out, 62 * NSEG);
}

// Round 10
// 146.326 us; speedup vs baseline: 1.0335x; 1.0335x over previous
//
#include <hip/hip_runtime.h>
#include <stdint.h>

#define OH 250
#define OW 250
#define NPTS (OH*OW)        // 62500
#define NSEG 4              // y batches only (x-side is mathematically dead; verified R2-R9)
#define D 147               // 3*7*7
#define CH 3
#define IMH 256
#define IMW 256
#define NITER 17            // ceil(log2(62500)) + 1, per reference
#define NBUCK 8192
#define CAP 128             // slots/bucket; central lambda ~24, P(>128) ~ 0
#define SIG0 12.124355652982141  // sqrt(147): projection stddev model (bucketing only)
#define LT 12               // probe-tree levels cached in LDS (nodes 1..4095)

typedef unsigned long long u64;
typedef unsigned int u32;

// workspace layout (bytes)
#define OFF_SREC  0UL          // u64[4*8192*128] = 33,554,432
#define OFF_A     33554432UL   // u32[4*62500]    = 1,000,000
#define OFF_CTRL  34554432UL   // zeroed by hipMemsetAsync each call:
#define OFF_CURS  34554432UL   //   u32[4*8192] = 131,072
#define OFF_SUMS  34685504UL   //   u64[4]      = 32
#define OFF_TICK  34685536UL   //   u32[2]      = 8
#define OFF_OFLOW 34685544UL   //   u32[1]      = 4
#define CTRL_LEN  131116UL
#define OFF_BASES 34685548UL   // u32[4*8193] = 131,088 (written by scan)
#define WS_NEED   34816636UL

__device__ __forceinline__ u64 packd(double f) {
  u64 u = (u64)__double_as_longlong(f);
  return (u & 0x8000000000000000ULL) ? ~u : (u | 0x8000000000000000ULL);
}

// bucket from the 47-bit-truncated transformed key (monotone with key order)
__device__ __forceinline__ int bucket_of(u64 rec) {
  u64 t = rec & ~0x1FFFFULL;
  u64 bits = (t & 0x8000000000000000ULL) ? (t & 0x7FFFFFFFFFFFFFFFULL) : ~t;
  double v = __longlong_as_double((long long)bits);
  double z = (v + 4.0 * SIG0) * ((double)NBUCK / (8.0 * SIG0));
  int b = (z <= 0.0) ? 0 : (int)z;
  if (b > NBUCK - 1) b = NBUCK - 1;
  return b;
}

// ---- conv (3x7x7, f64) + per-block weights + direct bucket scatter (no fences/tickets) ----
// grid dim3(16,16,NSEG), block 16x16. curs/sums/tick/oflow pre-zeroed by memset.
__global__ __launch_bounds__(256) void conv_kern(const float* __restrict__ y,
                                                 const float* __restrict__ rnd,
                                                 u64* __restrict__ srec,
                                                 u32* __restrict__ curs,
                                                 u32* __restrict__ oflow) {
  __shared__ float tile[CH][22][22];
  __shared__ double w[D];
  int b = blockIdx.z;
  const float* in = y + (size_t)b * CH * IMH * IMW;
  int bi = blockIdx.y * 16, bj = blockIdx.x * 16;
  int tid = threadIdx.y * 16 + threadIdx.x;
  int lane = tid & 63;

  // per-block weights: rand/std(ddof=1) in f64; butterfly order differs from the
  // reference only in last-ulp of std -> uniform positive scale -> ranks exact (R6-R9).
  {
    double v0 = (double)rnd[b * D + lane];
    double v1 = (double)rnd[b * D + lane + 64];
    double v2 = (lane + 128 < D) ? (double)rnd[b * D + lane + 128] : 0.0;
    double sm = v0 + v1 + v2;
    #pragma unroll
    for (int o = 32; o > 0; o >>= 1) sm += __shfl_xor(sm, o, 64);
    double mean = sm / (double)D;
    double d0 = v0 - mean, d1 = v1 - mean;
    double d2 = (lane + 128 < D) ? (v2 - mean) : 0.0;
    double ss = d0 * d0 + d1 * d1 + d2 * d2;
    #pragma unroll
    for (int o = 32; o > 0; o >>= 1) ss += __shfl_xor(ss, o, 64);
    double stdv = sqrt(ss / (double)(D - 1));
    w[lane] = v0 / stdv;                    // all 4 waves write identical values - benign
    w[lane + 64] = v1 / stdv;
    if (lane + 128 < D) w[lane + 128] = v2 / stdv;
  }
  for (int c = 0; c < CH; ++c)
    for (int t = tid; t < 22 * 22; t += 256) {
      int rr = t / 22, cc = t - rr * 22;
      int r = bi + rr, col = bj + cc;
      float v = 0.f;
      if (r < IMH && col < IMW) v = in[((size_t)c * IMH + r) * IMW + col];
      tile[c][rr][cc] = v;
    }
  __syncthreads();
  int i = bi + threadIdx.y, j = bj + threadIdx.x;
  if (i < OH && j < OW) {
    double acc = 0.0;
    #pragma unroll
    for (int c = 0; c < CH; ++c)
      #pragma unroll
      for (int ph = 0; ph < 7; ++ph)
        #pragma unroll
        for (int pw = 0; pw < 7; ++pw)
          acc = fma((double)tile[c][threadIdx.y + ph][threadIdx.x + pw],
                    w[c * 49 + ph * 7 + pw], acc);
    int n = i * OW + j;
    u64 rec = (packd(acc) & ~0x1FFFFULL) | (u64)(u32)n;
    int bk = b * NBUCK + bucket_of(rec);
    u32 pos = atomicAdd(&curs[bk], 1u);
    if (pos < CAP) srec[(size_t)bk * CAP + pos] = rec;
    else atomicOr(oflow, 1u);              // exactness tripwire (never expected)
  }
}

// ---- per-seg exclusive scan of 8192 bucket counts -> bases (kernel boundary = coherence) ----
__global__ __launch_bounds__(1024) void scan_kern(const u32* __restrict__ curs,
                                                  u32* __restrict__ bases,
                                                  u32* __restrict__ oflow) {
  __shared__ u32 part[1024];
  int seg = blockIdx.x, t = threadIdx.x;
  u32 c[8]; u32 run = 0;
  #pragma unroll
  for (int m = 0; m < 8; ++m) {
    u32 v = curs[seg * NBUCK + 8 * t + m];
    c[m] = v > CAP ? CAP : v;              // clamp: OOB-safety only (oflow flags exactness)
    run += c[m];
  }
  part[t] = run;
  __syncthreads();
  for (int off = 1; off < 1024; off <<= 1) {
    u32 v = (t >= off) ? part[t - off] : 0u;
    __syncthreads();
    part[t] += v;
    __syncthreads();
  }
  u32 ex = part[t] - run;
  #pragma unroll
  for (int m = 0; m < 8; ++m) {
    bases[seg * (NBUCK + 1) + 8 * t + m] = ex;
    ex += c[m];
  }
  if (t == 1023) {
    bases[seg * (NBUCK + 1) + NBUCK] = ex;
    if (ex != NPTS) atomicOr(oflow, 2u);   // loud tripwire
  }
}

// ---- one wave per bucket: exact rank sort (records all distinct), write argsort idx ----
__global__ __launch_bounds__(512) void bsort_kern(const u64* __restrict__ srec,
                                                  const u32* __restrict__ bases,
                                                  u32* __restrict__ a) {
  __shared__ u64 buf[8][CAP];
  int wid = threadIdx.x >> 6, lane = threadIdx.x & 63;
  int B = blockIdx.x * 8 + wid;            // 32768 buckets total
  int seg = B / NBUCK, bk = B & (NBUCK - 1);
  u32 b0 = bases[seg * (NBUCK + 1) + bk];
  u32 b1 = bases[seg * (NBUCK + 1) + bk + 1];
  int n = (int)(b1 - b0);                  // <= CAP by scan clamp
  const u64* src = srec + (size_t)B * CAP;
  u32* dst = a + (size_t)seg * NPTS + b0;
  for (int i = lane; i < n; i += 64) buf[wid][i] = src[i];
  __syncthreads();
  for (int i = lane; i < n; i += 64) {
    u64 x = buf[wid][i];
    int r = 0;
    for (int j = 0; j < n; ++j) r += (buf[wid][j] < x);   // LDS broadcast, conflict-free
    dst[r] = (u32)(x & 0x1FFFFULL);
  }
}

// ---- loss: exact bisect replica, 12-level LDS probe tree + 5 global probes; fused final ----
// grid (245, NSEG) x 256, one search per thread -> ~4 blocks/CU for latency hiding.
__global__ __launch_bounds__(256) void loss_kern(const u32* __restrict__ a_all,
                                                 u64* __restrict__ sums,
                                                 u32* __restrict__ tick,
                                                 const u32* __restrict__ oflow,
                                                 float* __restrict__ out,
                                                 int nblocks) {
  __shared__ u32 tval[1 << LT];            // 16 KB
  __shared__ u64 parts[4];
  __shared__ u32 rank_s;
  int tid = threadIdx.x;
  int seg = blockIdx.y;
  const u32* A = a_all + (size_t)seg * NPTS;
  // probe-value tree: node h's (lo,hi) state replayed from path bits; value = A[clip(mid)]
  for (int h = 1 + tid; h < (1 << LT); h += 256) {
    int d = 31 - __clz(h);
    int lo = 0, hi = NPTS;
    for (int k = d - 1; k >= 0; --k) {
      int mid = (lo + hi) >> 1;
      if (lo < hi) { if ((h >> k) & 1) lo = mid + 1; else hi = mid; }
    }
    int pos = (lo + hi) >> 1;
    if (pos > NPTS - 1) pos = NPTS - 1;
    tval[h] = A[pos];
  }
  __syncthreads();

  int v = blockIdx.x * 256 + tid;
  u64 tsum = 0;
  if (v < NPTS) {
    int lo = 0, hi = NPTS, h = 1;
    #pragma unroll
    for (int it = 0; it < LT; ++it) {      // LDS phase (probe value from tree)
      int am = (int)tval[h];
      bool pred = am < v;
      if (lo < hi) {
        int mid = (lo + hi) >> 1;
        if (pred) lo = mid + 1; else hi = mid;
      }
      h = 2 * h + (pred ? 1 : 0);
    }
    #pragma unroll
    for (int it = LT; it < NITER; ++it) {  // global phase
      int mid = (lo + hi) >> 1;
      int cm = mid > NPTS - 1 ? NPTS - 1 : mid;
      int am = (int)A[cm];
      if (lo < hi) { if (am < v) lo = mid + 1; else hi = mid; }
    }
    int pi = lo - 1; if (pi < 0) pi = 0; if (pi > NPTS - 1) pi = NPTS - 1;
    int ci = lo;     if (ci > NPTS - 1) ci = NPTS - 1;
    int ap = (int)A[pi], aa = (int)A[ci];
    int d1 = v - ap; if (d1 < 0) d1 = -d1;
    int d2 = v - aa; if (d2 < 0) d2 = -d2;
    bool tp = (lo > 0) && ((lo == NPTS) || (d1 < d2));
    long long dd = (long long)(v - (tp ? ap : aa));
    tsum = (u64)(dd * dd);
  }
  for (int off = 32; off > 0; off >>= 1) tsum += __shfl_down(tsum, off, 64);
  int lane = tid & 63, wid = tid >> 6;
  if (lane == 0) parts[wid] = tsum;
  __syncthreads();
  if (tid == 0) {
    u64 bsum = parts[0] + parts[1] + parts[2] + parts[3];
    u64 old = atomicAdd(&sums[seg], bsum);
    asm volatile("" : : "v"(old) : "memory");      // RMW completion before ticket
    rank_s = atomicAdd(&tick[1], 1u);
    if (rank_s == (u32)(nblocks - 1)) {            // fence-free fused final (validated R9)
      u32 of = __hip_atomic_load(oflow, __ATOMIC_RELAXED, __HIP_MEMORY_SCOPE_AGENT);
      if (of) { out[0] = 8.0e12f + 1.0e11f * (float)of; return; }
      double l = 0.0;
      for (int s = 0; s < NSEG; ++s) {
        u64 sv = __hip_atomic_load(&sums[s], __ATOMIC_RELAXED, __HIP_MEMORY_SCOPE_AGENT);
        l += (double)(long long)sv / (double)NPTS;
      }
      out[0] = (float)(l / 4.0);
    }
  }
}

__global__ void guard_kern(float* __restrict__ out) {
  if (threadIdx.x == 0 && blockIdx.x == 0) out[0] = 9.0e12f;
}

extern "C" void kernel_launch(void* const* d_in, const int* in_sizes, int n_in,
                              void* d_out, int out_size, void* d_ws, size_t ws_size,
                              hipStream_t stream) {
  (void)in_sizes; (void)n_in; (void)out_size;
  if (ws_size < WS_NEED) { guard_kern<<<1, 64, 0, stream>>>((float*)d_out); return; }
  const float* y   = (const float*)d_in[1];
  const float* rnd = (const float*)d_in[2];

  char* ws = (char*)d_ws;
  u64* srec   = (u64*)(ws + OFF_SREC);
  u32* aidx   = (u32*)(ws + OFF_A);
  u32* curs   = (u32*)(ws + OFF_CURS);
  u64* sums   = (u64*)(ws + OFF_SUMS);
  u32* tick   = (u32*)(ws + OFF_TICK);
  u32* oflow  = (u32*)(ws + OFF_OFLOW);
  u32* bases  = (u32*)(ws + OFF_BASES);
  float* out  = (float*)d_out;

  hipMemsetAsync(ws + OFF_CTRL, 0, CTRL_LEN, stream);
  conv_kern<<<dim3(16, 16, NSEG), dim3(16, 16), 0, stream>>>(y, rnd, srec, curs, oflow);
  scan_kern<<<NSEG, 1024, 0, stream>>>(curs, bases, oflow);
  bsort_kern<<<NSEG * NBUCK / 8, 512, 0, stream>>>(srec, bases, aidx);
  int nb = 245 * NSEG;
  loss_kern<<<dim3(245, NSEG), 256, 0, stream>>>(aidx, sums, tick, oflow, out, nb);
}

// Round 11
// 117.807 us; speedup vs baseline: 1.2837x; 1.2421x over previous
//
#include <hip/hip_runtime.h>
#include <stdint.h>

#define OH 250
#define OW 250
#define NPTS (OH*OW)        // 62500
#define NSEG 4              // y batches only (x-side is mathematically dead; verified R2-R10)
#define D 147               // 3*7*7
#define CH 3
#define IMH 256
#define IMW 256
#define NITER 17            // ceil(log2(62500)) + 1, per reference
#define NBUCK 8192
#define CAP 128             // slots/bucket; central lambda ~24, P(>128) ~ 0
#define SIG0 12.124355652982141  // sqrt(147): projection stddev model (bucketing only)

typedef unsigned long long u64;
typedef unsigned int u32;

// workspace layout (bytes)
#define OFF_SREC  0UL          // u64[4*8192*128] = 33,554,432
#define OFF_A     33554432UL   // u32[4*62500]    = 1,000,000
#define OFF_WTS   34554432UL   // f64[4*147]      = 4,704
#define OFF_CURS  34559136UL   // u32[4*8192]     = 131,072
#define OFF_BASES 34690208UL   // u32[4*8193]     = 131,088
#define OFF_SUMS  34821296UL   // u64[4]          = 32
#define OFF_TICK  34821328UL   // u32[2]          = 8
#define OFF_OFLOW 34821336UL   // u32[1]          = 4
#define WS_NEED   34821340UL

__device__ __forceinline__ u64 packd(double f) {
  u64 u = (u64)__double_as_longlong(f);
  return (u & 0x8000000000000000ULL) ? ~u : (u | 0x8000000000000000ULL);
}

// bucket from the 47-bit-truncated transformed key (monotone with key order)
__device__ __forceinline__ int bucket_of(u64 rec) {
  u64 t = rec & ~0x1FFFFULL;
  u64 bits = (t & 0x8000000000000000ULL) ? (t & 0x7FFFFFFFFFFFFFFFULL) : ~t;
  double v = __longlong_as_double((long long)bits);
  double z = (v + 4.0 * SIG0) * ((double)NBUCK / (8.0 * SIG0));
  int b = (z <= 0.0) ? 0 : (int)z;
  if (b > NBUCK - 1) b = NBUCK - 1;
  return b;
}

// ---- setup: blocks 0..3 weights (rand/std ddof=1, f64 -> global); blocks 4..35 zero ctrl ----
__global__ __launch_bounds__(256) void setup_kern(const float* __restrict__ rnd,
                                                  double* __restrict__ wts,
                                                  u32* __restrict__ curs,
                                                  u64* __restrict__ sums,
                                                  u32* __restrict__ tick,
                                                  u32* __restrict__ oflow) {
  int t = threadIdx.x;
  if (blockIdx.x < 4) {
    int b = blockIdx.x;
    int lane = t & 63;
    double v0 = (double)rnd[b * D + lane];
    double v1 = (double)rnd[b * D + lane + 64];
    double v2 = (lane + 128 < D) ? (double)rnd[b * D + lane + 128] : 0.0;
    double sm = v0 + v1 + v2;
    #pragma unroll
    for (int o = 32; o > 0; o >>= 1) sm += __shfl_xor(sm, o, 64);
    double mean = sm / (double)D;
    double d0 = v0 - mean, d1 = v1 - mean;
    double d2 = (lane + 128 < D) ? (v2 - mean) : 0.0;
    double ss = d0 * d0 + d1 * d1 + d2 * d2;
    #pragma unroll
    for (int o = 32; o > 0; o >>= 1) ss += __shfl_xor(ss, o, 64);
    double stdv = sqrt(ss / (double)(D - 1));
    if (t < 64) {                                  // one wave writes
      wts[b * D + lane] = v0 / stdv;
      wts[b * D + lane + 64] = v1 / stdv;
      if (lane + 128 < D) wts[b * D + lane + 128] = v2 / stdv;
    }
    if (b == 0 && t < 8) ((u32*)sums)[t] = 0u;
    if (b == 0 && t >= 8 && t < 10) tick[t - 8] = 0u;
    if (b == 0 && t == 10) oflow[0] = 0u;
  } else {
    int g = (blockIdx.x - 4) * 1024 + t * 4;       // 32 blocks cover 32768 u32
    if (g < NSEG * NBUCK) {
      curs[g] = 0u; curs[g + 1] = 0u; curs[g + 2] = 0u; curs[g + 3] = 0u;
    }
  }
}

// ---- conv (3x7x7, f64) + direct bucket scatter. Weights via wave-uniform global loads
// (scalar pipe, K$) -> no LDS traffic for w; 3-way split acc breaks the serial FMA chain
// (f64 reassociation noise ~1e-13 rel << rank gaps ~1e-3 rel -> ranks unchanged). ----
__global__ __launch_bounds__(256) void conv_kern(const float* __restrict__ y,
                                                 const double* __restrict__ wts,
                                                 u64* __restrict__ srec,
                                                 u32* __restrict__ curs,
                                                 u32* __restrict__ oflow) {
  __shared__ float tile[CH][22][22];
  int b = blockIdx.z;
  const float* in = y + (size_t)b * CH * IMH * IMW;
  const double* wb = wts + b * D;                  // uniform base -> s_load per tap
  int bi = blockIdx.y * 16, bj = blockIdx.x * 16;
  int tid = threadIdx.y * 16 + threadIdx.x;
  for (int c = 0; c < CH; ++c)
    for (int t = tid; t < 22 * 22; t += 256) {
      int rr = t / 22, cc = t - rr * 22;
      int r = bi + rr, col = bj + cc;
      float v = 0.f;
      if (r < IMH && col < IMW) v = in[((size_t)c * IMH + r) * IMW + col];
      tile[c][rr][cc] = v;
    }
  __syncthreads();
  int i = bi + threadIdx.y, j = bj + threadIdx.x;
  if (i < OH && j < OW) {
    double acc = 0.0;
    #pragma unroll
    for (int c = 0; c < CH; ++c) {
      double ac = 0.0;                             // per-channel partial: 3 short chains
      #pragma unroll
      for (int ph = 0; ph < 7; ++ph)
        #pragma unroll
        for (int pw = 0; pw < 7; ++pw)
          ac = fma((double)tile[c][threadIdx.y + ph][threadIdx.x + pw],
                   wb[c * 49 + ph * 7 + pw], ac);
      acc += ac;
    }
    int n = i * OW + j;
    u64 rec = (packd(acc) & ~0x1FFFFULL) | (u64)(u32)n;
    int bk = b * NBUCK + bucket_of(rec);
    u32 pos = atomicAdd(&curs[bk], 1u);
    if (pos < CAP) srec[(size_t)bk * CAP + pos] = rec;
    else atomicOr(oflow, 1u);                      // exactness tripwire (never expected)
  }
}

// ---- per-seg exclusive scan of 8192 bucket counts -> bases (kernel boundary = coherence) ----
__global__ __launch_bounds__(1024) void scan_kern(const u32* __restrict__ curs,
                                                  u32* __restrict__ bases,
                                                  u32* __restrict__ oflow) {
  __shared__ u32 part[1024];
  int seg = blockIdx.x, t = threadIdx.x;
  u32 c[8]; u32 run = 0;
  #pragma unroll
  for (int m = 0; m < 8; ++m) {
    u32 v = curs[seg * NBUCK + 8 * t + m];
    c[m] = v > CAP ? CAP : v;                      // clamp: OOB-safety only
    run += c[m];
  }
  part[t] = run;
  __syncthreads();
  for (int off = 1; off < 1024; off <<= 1) {
    u32 v = (t >= off) ? part[t - off] : 0u;
    __syncthreads();
    part[t] += v;
    __syncthreads();
  }
  u32 ex = part[t] - run;
  #pragma unroll
  for (int m = 0; m < 8; ++m) {
    bases[seg * (NBUCK + 1) + 8 * t + m] = ex;
    ex += c[m];
  }
  if (t == 1023) {
    bases[seg * (NBUCK + 1) + NBUCK] = ex;
    if (ex != NPTS) atomicOr(oflow, 2u);           // loud tripwire
  }
}

// ---- one wave per bucket: exact rank sort (records all distinct), write argsort idx ----
__global__ __launch_bounds__(512) void bsort_kern(const u64* __restrict__ srec,
                                                  const u32* __restrict__ bases,
                                                  u32* __restrict__ a) {
  __shared__ u64 buf[8][CAP];
  int wid = threadIdx.x >> 6, lane = threadIdx.x & 63;
  int B = blockIdx.x * 8 + wid;                    // 32768 buckets total
  int seg = B / NBUCK, bk = B & (NBUCK - 1);
  u32 b0 = bases[seg * (NBUCK + 1) + bk];
  u32 b1 = bases[seg * (NBUCK + 1) + bk + 1];
  int n = (int)(b1 - b0);                          // <= CAP by scan clamp
  const u64* src = srec + (size_t)B * CAP;
  u32* dst = a + (size_t)seg * NPTS + b0;
  for (int i = lane; i < n; i += 64) buf[wid][i] = src[i];
  __syncthreads();
  for (int i = lane; i < n; i += 64) {
    u64 x = buf[wid][i];
    int r = 0;
    for (int j = 0; j < n; ++j) r += (buf[wid][j] < x);   // LDS broadcast, conflict-free
    dst[r] = (u32)(x & 0x1FFFFULL);
  }
}

// ---- loss: exact replica bisect_left-on-unsorted + nearest; two interleaved chains per
// thread (R8-proven); fence-free fused final (validated R9/R10). ----
#define HALF (NSEG * NPTS / 2)                     // 125000
__global__ __launch_bounds__(256) void loss_kern(const u32* __restrict__ a_all,
                                                 u64* __restrict__ sums,
                                                 u32* __restrict__ tick,
                                                 const u32* __restrict__ oflow,
                                                 float* __restrict__ out,
                                                 int nblocks) {
  __shared__ u64 lsums[NSEG];
  __shared__ u32 rank_s;
  int tid = threadIdx.x;
  if (tid < NSEG) lsums[tid] = 0ULL;
  __syncthreads();
  int g = blockIdx.x * 256 + tid;
  if (g < HALF) {
    int g1 = g + HALF;
    int s0 = g / NPTS, s1 = g1 / NPTS;
    int vv0 = g - s0 * NPTS, vv1 = g1 - s1 * NPTS;
    const u32* A0 = a_all + (size_t)s0 * NPTS;
    const u32* A1 = a_all + (size_t)s1 * NPTS;
    int lo0 = 0, hi0 = NPTS, lo1 = 0, hi1 = NPTS;
    #pragma unroll
    for (int it = 0; it < NITER; ++it) {
      int mid0 = (lo0 + hi0) >> 1, mid1 = (lo1 + hi1) >> 1;
      int cm0 = mid0 > NPTS - 1 ? NPTS - 1 : mid0;
      int cm1 = mid1 > NPTS - 1 ? NPTS - 1 : mid1;
      int am0 = (int)A0[cm0];                      // two independent dependent-load chains
      int am1 = (int)A1[cm1];
      if (lo0 < hi0) { if (am0 < vv0) lo0 = mid0 + 1; else hi0 = mid0; }
      if (lo1 < hi1) { if (am1 < vv1) lo1 = mid1 + 1; else hi1 = mid1; }
    }
    {
      int pi = lo0 - 1; if (pi < 0) pi = 0; if (pi > NPTS - 1) pi = NPTS - 1;
      int ci = lo0;     if (ci > NPTS - 1) ci = NPTS - 1;
      int ap = (int)A0[pi], aa = (int)A0[ci];
      int d1 = vv0 - ap; if (d1 < 0) d1 = -d1;
      int d2 = vv0 - aa; if (d2 < 0) d2 = -d2;
      bool tp = (lo0 > 0) && ((lo0 == NPTS) || (d1 < d2));
      long long dd = (long long)(vv0 - (tp ? ap : aa));
      atomicAdd(&lsums[s0], (u64)(dd * dd));
    }
    {
      int pi = lo1 - 1; if (pi < 0) pi = 0; if (pi > NPTS - 1) pi = NPTS - 1;
      int ci = lo1;     if (ci > NPTS - 1) ci = NPTS - 1;
      int ap = (int)A1[pi], aa = (int)A1[ci];
      int d1 = vv1 - ap; if (d1 < 0) d1 = -d1;
      int d2 = vv1 - aa; if (d2 < 0) d2 = -d2;
      bool tp = (lo1 > 0) && ((lo1 == NPTS) || (d1 < d2));
      long long dd = (long long)(vv1 - (tp ? ap : aa));
      atomicAdd(&lsums[s1], (u64)(dd * dd));
    }
  }
  __syncthreads();
  if (tid < NSEG && lsums[tid]) atomicAdd(&sums[tid], lsums[tid]);
  __syncthreads();                                 // implies vmcnt(0): sums RMWs complete
  if (tid == 0) {
    rank_s = atomicAdd(&tick[1], 1u);
    if (rank_s == (u32)(nblocks - 1)) {            // fence-free fused final
      u32 of = __hip_atomic_load(oflow, __ATOMIC_RELAXED, __HIP_MEMORY_SCOPE_AGENT);
      if (of) { out[0] = 8.0e12f + 1.0e11f * (float)of; return; }
      double l = 0.0;
      for (int s = 0; s < NSEG; ++s) {
        u64 sv = __hip_atomic_load(&sums[s], __ATOMIC_RELAXED, __HIP_MEMORY_SCOPE_AGENT);
        l += (double)(long long)sv / (double)NPTS;
      }
      out[0] = (float)(l / 4.0);
    }
  }
}

__global__ void guard_kern(float* __restrict__ out) {
  if (threadIdx.x == 0 && blockIdx.x == 0) out[0] = 9.0e12f;
}

extern "C" void kernel_launch(void* const* d_in, const int* in_sizes, int n_in,
                              void* d_out, int out_size, void* d_ws, size_t ws_size,
                              hipStream_t stream) {
  (void)in_sizes; (void)n_in; (void)out_size;
  if (ws_size < WS_NEED) { guard_kern<<<1, 64, 0, stream>>>((float*)d_out); return; }
  const float* y   = (const float*)d_in[1];
  const float* rnd = (const float*)d_in[2];

  char* ws = (char*)d_ws;
  u64* srec   = (u64*)(ws + OFF_SREC);
  u32* aidx   = (u32*)(ws + OFF_A);
  double* wts = (double*)(ws + OFF_WTS);
  u32* curs   = (u32*)(ws + OFF_CURS);
  u32* bases  = (u32*)(ws + OFF_BASES);
  u64* sums   = (u64*)(ws + OFF_SUMS);
  u32* tick   = (u32*)(ws + OFF_TICK);
  u32* oflow  = (u32*)(ws + OFF_OFLOW);
  float* out  = (float*)d_out;

  setup_kern<<<36, 256, 0, stream>>>(rnd, wts, curs, sums, tick, oflow);
  conv_kern<<<dim3(16, 16, NSEG), dim3(16, 16), 0, stream>>>(y, wts, srec, curs, oflow);
  scan_kern<<<NSEG, 1024, 0, stream>>>(curs, bases, oflow);
  bsort_kern<<<NSEG * NBUCK / 8, 512, 0, stream>>>(srec, bases, aidx);
  int nb = (HALF + 255) / 256;                     // 489
  loss_kern<<<nb, 256, 0, stream>>>(aidx, sums, tick, oflow, out, nb);
}